// Round 7
// baseline (1141.931 us; speedup 1.0000x reference)
//
#include <hip/hip_runtime.h>

#define N_NODES 100000
#define IN_CH   256
#define HID_D   64
#define NCLS    6
#define NE      1600000

typedef unsigned int u32;

// ws layout (bytes)
#define OFF_CNT   0u          // 100000*4 = 400000
#define OFF_A     400128u     // 25,600,000 B f32
#define OFF_B     26000128u   // 25,600,000 B f32 -> end 51,600,128
#define Z_OFF     600000u     // d_out (f32): logits [0,600000), z [600000,7000000)

// ---- in-degree over dst (planar (2,E) int32) ----
__global__ __launch_bounds__(256) void k_deg(const int* __restrict__ ei,
                                             int* __restrict__ cnt) {
    int e = blockIdx.x * 256 + threadIdx.x;
    int d = ei[NE + e];
    if ((u32)d < (u32)N_NODES) atomicAdd(&cnt[d], 1);
}

// ---- g = dinv .* (x @ W1); AGG = g ----
__global__ __launch_bounds__(256) void k_mmx(const float* __restrict__ X,
                                             const float* __restrict__ W,
                                             const int* __restrict__ cnt,
                                             float* __restrict__ G,
                                             float* __restrict__ AGG) {
    __shared__ float sx[4][IN_CH];
    const int wv = threadIdx.x >> 6;
    const int c  = threadIdx.x & 63;
    const int node = blockIdx.x * 4 + wv;

    const float* xp = X + (size_t)node * IN_CH;
    for (int k = c; k < IN_CH; k += 64) sx[wv][k] = xp[k];
    __syncthreads();

    float acc = 0.f;
#pragma unroll 8
    for (int k = 0; k < IN_CH; ++k)
        acc += sx[wv][k] * W[k * 64 + c];

    float dinv = rsqrtf((float)(cnt[node] + 1));
    float g = acc * dinv;
    G[(size_t)node * 64 + c] = g;
    AGG[(size_t)node * 64 + c] = g;
}

// ---- g2 = dinv .* (A @ W), K = 64 ----
__global__ __launch_bounds__(256) void k_mm64(const float* __restrict__ A,
                                              const float* __restrict__ W,
                                              const int* __restrict__ cnt,
                                              float* __restrict__ G) {
    __shared__ float sx[4][HID_D];
    const int wv = threadIdx.x >> 6;
    const int c  = threadIdx.x & 63;
    const int node = blockIdx.x * 4 + wv;

    sx[wv][c] = A[(size_t)node * HID_D + c];
    __syncthreads();

    float acc = 0.f;
#pragma unroll 8
    for (int k = 0; k < HID_D; ++k)
        acc += sx[wv][k] * W[k * 64 + c];

    float dinv = rsqrtf((float)(cnt[node] + 1));
    G[(size_t)node * 64 + c] = acc * dinv;
}

// ---- DST[dst][c] += SRC[src][c] over edges (planar int32) ----
__global__ __launch_bounds__(256) void k_edge(const int* __restrict__ ei,
                                              const float* __restrict__ SRC,
                                              float* __restrict__ DST) {
    const int wv = threadIdx.x >> 6;
    const int c  = threadIdx.x & 63;
    const int e  = blockIdx.x * 4 + wv;
    int s = ei[e];
    int d = ei[NE + e];
    if ((u32)s >= (u32)N_NODES || (u32)d >= (u32)N_NODES) return;
    float v = SRC[(size_t)s * 64 + c];
    atomicAdd(&DST[(size_t)d * 64 + c], v);
}

// ---- OUT = relu(dinv .* AGG + b) ----
__global__ __launch_bounds__(256) void k_post(const float* __restrict__ AGG,
                                              const int* __restrict__ cnt,
                                              const float* __restrict__ b,
                                              float* __restrict__ OUT) {
    int i = blockIdx.x * 256 + threadIdx.x;
    int node = i >> 6, c = i & 63;
    float dinv = rsqrtf((float)(cnt[node] + 1));
    OUT[i] = fmaxf(AGG[i] * dinv + b[c], 0.f);
}

__global__ __launch_bounds__(256) void k_copy(const float4* __restrict__ src,
                                              float4* __restrict__ dst) {
    int i = blockIdx.x * 256 + threadIdx.x;
    dst[i] = src[i];
}

// ---- z = relu(H@Wp+bp) -> out f32; logits = z@Wc+bc -> out f32 ----
__global__ __launch_bounds__(256) void k_mlp(const float* __restrict__ H,
                                             const float* __restrict__ Wp,
                                             const float* __restrict__ bp,
                                             const float* __restrict__ Wc,
                                             const float* __restrict__ bc,
                                             float* __restrict__ out) {
    __shared__ float sh[4][64];
    __shared__ float sz[4][64];
    const int wv = threadIdx.x >> 6;
    const int c  = threadIdx.x & 63;
    const int node = blockIdx.x * 4 + wv;

    sh[wv][c] = H[(size_t)node * 64 + c];
    __syncthreads();

    float acc = bp[c];
#pragma unroll 8
    for (int k = 0; k < 64; ++k)
        acc += sh[wv][k] * Wp[k * 64 + c];
    acc = fmaxf(acc, 0.f);
    sz[wv][c] = acc;
    out[Z_OFF + (size_t)node * 64 + c] = acc;
    __syncthreads();

    if (c < NCLS) {
        float l = bc[c];
#pragma unroll 8
        for (int k = 0; k < 64; ++k)
            l += sz[wv][k] * Wc[k * NCLS + c];
        out[(size_t)node * NCLS + c] = l;
    }
}

extern "C" void kernel_launch(void* const* d_in, const int* in_sizes, int n_in,
                              void* d_out, int out_size, void* d_ws, size_t ws_size,
                              hipStream_t stream) {
    const float* x  = (const float*)d_in[0];
    const int*   ei = (const int*)d_in[1];
    const float* W1 = (const float*)d_in[2];
    const float* b1 = (const float*)d_in[3];
    const float* W2 = (const float*)d_in[4];
    const float* b2 = (const float*)d_in[5];
    const float* Wp = (const float*)d_in[6];
    const float* bp = (const float*)d_in[7];
    const float* Wc = (const float*)d_in[8];
    const float* bc = (const float*)d_in[9];
    float* out = (float*)d_out;

    char*  ws   = (char*)d_ws;
    int*   cnt  = (int*)(ws + OFF_CNT);
    float* bufA = (float*)(ws + OFF_A);
    float* bufB = (float*)(ws + OFF_B);

    hipMemsetAsync(ws, 0, OFF_A, stream);                       // cnt
    k_deg<<<NE / 256, 256, 0, stream>>>(ei, cnt);

    // layer 1: bufA = g1, bufB = g1 + scatter(g1); bufA = h1
    k_mmx<<<N_NODES / 4, 256, 0, stream>>>(x, W1, cnt, bufA, bufB);
    k_edge<<<NE / 4, 256, 0, stream>>>(ei, bufA, bufB);
    k_post<<<N_NODES * 64 / 256, 256, 0, stream>>>(bufB, cnt, b1, bufA);

    // layer 2: bufB = g2; bufA = g2 + scatter(g2); bufB = h2
    k_mm64<<<N_NODES / 4, 256, 0, stream>>>(bufA, W2, cnt, bufB);
    k_copy<<<N_NODES * 64 / 4 / 256, 256, 0, stream>>>((const float4*)bufB, (float4*)bufA);
    k_edge<<<NE / 4, 256, 0, stream>>>(ei, bufB, bufA);
    k_post<<<N_NODES * 64 / 256, 256, 0, stream>>>(bufA, cnt, b2, bufB);

    k_mlp<<<N_NODES / 4, 256, 0, stream>>>(bufB, Wp, bp, Wc, bc, out);
}

// Round 8
// 296.400 us; speedup vs baseline: 3.8527x; 3.8527x over previous
//
#include <hip/hip_runtime.h>

#define N_NODES 100000
#define IN_CH   256
#define HID_D   64
#define NCLS    6
#define NE      1600000
#define WB      64          // padded bucket width per node
#define OVF_CAP 4096

typedef unsigned short u16;
typedef unsigned int   u32;
typedef __attribute__((ext_vector_type(8))) short bf16x8;
typedef __attribute__((ext_vector_type(4))) float f32x4;

// ws layout (bytes)
#define OFF_CNT   0u                       // 100000*4 = 400000
#define OFF_OVFC  400000u                  // 4
#define OFF_OVF   400128u                  // 4096*2*4 = 32768
#define OFF_COL   433152u                  // 100000*64*4 = 25,600,000
#define OFF_G     26033152u                // 100000*64*2 = 12,800,000 (bf16)
#define OFF_H     38833152u                // 12,800,000 (bf16) -> end 51,633,152
#define Z_OFF     600000u                  // d_out (f32): logits [0,600000), z rest

__device__ __forceinline__ u16 f2bf(float f) {
    u32 u = __float_as_uint(f);
    return (u16)((u + 0x7fffu + ((u >> 16) & 1u)) >> 16);   // RNE
}
__device__ __forceinline__ float bf2f(u16 h) {
    return __uint_as_float(((u32)h) << 16);
}

// ---- build per-dst padded edge buckets; cnt ends as in-degree ----
__global__ __launch_bounds__(256) void k_fill(const int* __restrict__ ei,
                                              int* __restrict__ cnt,
                                              int* __restrict__ col,
                                              int* __restrict__ ovfc,
                                              int* __restrict__ ovf) {
    int e = blockIdx.x * 256 + threadIdx.x;          // grid exact: NE/256
    int s = ei[e];
    int d = ei[NE + e];
    if ((u32)s >= (u32)N_NODES || (u32)d >= (u32)N_NODES) return;
    int p = atomicAdd(&cnt[d], 1);
    if (p < WB) {
        col[(size_t)d * WB + p] = s;
    } else {
        int k = atomicAdd(ovfc, 1);
        if (k < OVF_CAP) { ovf[2 * k] = s; ovf[2 * k + 1] = d; }
    }
}

// ---- G(bf16) = dinv .* (A @ W); A f32 or bf16 [N,KDIM], W f32 [KDIM,64] ----
template <int KDIM, bool ABF16>
__global__ __launch_bounds__(256) void k_gemm(const void* __restrict__ A,
                                              const float* __restrict__ W,
                                              const int* __restrict__ cnt,
                                              u16* __restrict__ G) {
    constexpr int KK = KDIM / 32;
    __shared__ __align__(16) u16 sB[KK * 4 * 64 * 8];

    // stage W into fragment-ordered LDS (bf16): slot(kk,t,l,j) <- W[k][c],
    // k = kk*32+(l>>4)*8+j, c = t*16+(l&15)  (same (lane,j)->k map as A)
    for (int idx = threadIdx.x; idx < KK * 2048; idx += 256) {
        int j = idx & 7, l = (idx >> 3) & 63, t = (idx >> 9) & 3, kk = idx >> 11;
        int k = kk * 32 + (l >> 4) * 8 + j;
        int c = t * 16 + (l & 15);
        sB[idx] = f2bf(W[k * 64 + c]);
    }
    __syncthreads();

    const int lane = threadIdx.x & 63;
    const int wv   = threadIdx.x >> 6;
    const int row0 = blockIdx.x * 64 + wv * 16;
    const int g4   = lane >> 4;
    const int r16  = lane & 15;

    int arow = row0 + r16;
    int arow_c = arow < N_NODES ? arow : 0;

    f32x4 acc[4] = {{0,0,0,0},{0,0,0,0},{0,0,0,0},{0,0,0,0}};

    for (int kk = 0; kk < KK; ++kk) {
        bf16x8 a;
        if (ABF16) {
            const u16* ap = (const u16*)A + (size_t)arow_c * KDIM + kk * 32 + g4 * 8;
            a = *(const bf16x8*)ap;
        } else {
            const float* ap = (const float*)A + (size_t)arow_c * KDIM + kk * 32 + g4 * 8;
            float4 f0 = *(const float4*)ap;
            float4 f1 = *(const float4*)(ap + 4);
            a[0] = (short)f2bf(f0.x); a[1] = (short)f2bf(f0.y);
            a[2] = (short)f2bf(f0.z); a[3] = (short)f2bf(f0.w);
            a[4] = (short)f2bf(f1.x); a[5] = (short)f2bf(f1.y);
            a[6] = (short)f2bf(f1.z); a[7] = (short)f2bf(f1.w);
        }
#pragma unroll
        for (int t = 0; t < 4; ++t) {
            bf16x8 b = *(const bf16x8*)&sB[((kk * 4 + t) * 64 + lane) * 8];
            acc[t] = __builtin_amdgcn_mfma_f32_16x16x32_bf16(a, b, acc[t], 0, 0, 0);
        }
    }

    // C/D: row=(lane>>4)*4+reg, col=lane&15 (m89/m91-verified)
#pragma unroll
    for (int r = 0; r < 4; ++r) {
        int row = row0 + g4 * 4 + r;
        if (row < N_NODES) {
            float dinv = rsqrtf((float)(cnt[row] + 1));
#pragma unroll
            for (int t = 0; t < 4; ++t)
                G[(size_t)row * 64 + t * 16 + r16] = f2bf(acc[t][r] * dinv);
        }
    }
}

// ---- Hout(bf16) = relu(dinv[i]*(g[i] + sum_{e:dst=i} g[src_e]) + bias) ----
__global__ __launch_bounds__(256) void k_agg(const u16* __restrict__ G,
                                             const int* __restrict__ col,
                                             const int* __restrict__ cnt,
                                             const int* __restrict__ ovfc,
                                             const int* __restrict__ ovf,
                                             const float* __restrict__ bias,
                                             u16* __restrict__ Hout) {
    int node = blockIdx.x * 4 + (threadIdx.x >> 6);   // grid exact: N/4
    int lane = threadIdx.x & 63;

    int deg = cnt[node];
    int m = min(deg, WB);
    int mycol = col[(size_t)node * WB + lane];

    float acc = bf2f(G[(size_t)node * 64 + lane]);    // self loop

    int e = 0;
    for (; e + 4 <= m; e += 4) {
        int c0 = __shfl(mycol, e + 0), c1 = __shfl(mycol, e + 1);
        int c2 = __shfl(mycol, e + 2), c3 = __shfl(mycol, e + 3);
        float v0 = bf2f(G[(size_t)c0 * 64 + lane]);
        float v1 = bf2f(G[(size_t)c1 * 64 + lane]);
        float v2 = bf2f(G[(size_t)c2 * 64 + lane]);
        float v3 = bf2f(G[(size_t)c3 * 64 + lane]);
        acc += v0; acc += v1; acc += v2; acc += v3;
    }
    for (; e < m; ++e) {
        int c = __shfl(mycol, e);
        acc += bf2f(G[(size_t)c * 64 + lane]);
    }

    int no = *ovfc;
    if (no > 0) {                       // essentially never taken (deg>64)
        no = min(no, OVF_CAP);
        for (int j = 0; j < no; ++j)
            if (ovf[2 * j + 1] == node)
                acc += bf2f(G[(size_t)ovf[2 * j] * 64 + lane]);
    }

    float dinv = rsqrtf((float)(deg + 1));
    float v = fmaxf(acc * dinv + bias[lane], 0.f);
    Hout[(size_t)node * 64 + lane] = f2bf(v);
}

// ---- z = relu(H@Wp+bp) -> out f32 [Z_OFF..]; logits = z@Wc+bc -> out f32 ----
__global__ __launch_bounds__(256) void k_mlp(const u16* __restrict__ H,
                                             const float* __restrict__ Wp,
                                             const float* __restrict__ bp,
                                             const float* __restrict__ Wc,
                                             const float* __restrict__ bc,
                                             float* __restrict__ out) {
    __shared__ __align__(16) u16 sP[2 * 4 * 64 * 8];
    __shared__ __align__(16) u16 sC[2 * 64 * 8];
    __shared__ __align__(16) u16 zt[4][16][72];

    for (int idx = threadIdx.x; idx < 4096; idx += 256) {
        int j = idx & 7, l = (idx >> 3) & 63, t = (idx >> 9) & 3, kk = idx >> 11;
        int k = kk * 32 + (l >> 4) * 8 + j;
        int c = t * 16 + (l & 15);
        sP[idx] = f2bf(Wp[k * 64 + c]);
    }
    for (int idx = threadIdx.x; idx < 1024; idx += 256) {
        int j = idx & 7, l = (idx >> 3) & 63, kk = idx >> 9;
        int k = kk * 32 + (l >> 4) * 8 + j;
        int c = l & 15;
        sC[idx] = (c < NCLS) ? f2bf(Wc[k * NCLS + c]) : (u16)0;
    }
    __syncthreads();

    const int lane = threadIdx.x & 63;
    const int wv   = threadIdx.x >> 6;
    const int row0 = blockIdx.x * 64 + wv * 16;
    const int g4   = lane >> 4;
    const int r16  = lane & 15;

    int arow = row0 + r16;
    int arow_c = arow < N_NODES ? arow : (N_NODES - 1);

    f32x4 zac[4] = {{0,0,0,0},{0,0,0,0},{0,0,0,0},{0,0,0,0}};
#pragma unroll
    for (int kk = 0; kk < 2; ++kk) {
        bf16x8 a = *(const bf16x8*)((const u16*)H + (size_t)arow_c * 64 + kk * 32 + g4 * 8);
#pragma unroll
        for (int t = 0; t < 4; ++t) {
            bf16x8 b = *(const bf16x8*)&sP[((kk * 4 + t) * 64 + lane) * 8];
            zac[t] = __builtin_amdgcn_mfma_f32_16x16x32_bf16(a, b, zac[t], 0, 0, 0);
        }
    }

#pragma unroll
    for (int r = 0; r < 4; ++r) {
        int row = row0 + g4 * 4 + r;
#pragma unroll
        for (int t = 0; t < 4; ++t) {
            float v = zac[t][r] + bp[t * 16 + r16];
            v = fmaxf(v, 0.f);
            zt[wv][g4 * 4 + r][t * 16 + r16] = f2bf(v);
            if (row < N_NODES)
                out[(size_t)Z_OFF + (size_t)row * 64 + t * 16 + r16] = v;
        }
    }
    __syncthreads();

    f32x4 lac = {0, 0, 0, 0};
#pragma unroll
    for (int kk = 0; kk < 2; ++kk) {
        bf16x8 a = *(const bf16x8*)&zt[wv][r16][kk * 32 + g4 * 8];
        bf16x8 b = *(const bf16x8*)&sC[(kk * 64 + lane) * 8];
        lac = __builtin_amdgcn_mfma_f32_16x16x32_bf16(a, b, lac, 0, 0, 0);
    }
#pragma unroll
    for (int r = 0; r < 4; ++r) {
        int row = row0 + g4 * 4 + r;
        if (row < N_NODES && r16 < NCLS)
            out[(size_t)row * NCLS + r16] = lac[r] + bc[r16];
    }
}

extern "C" void kernel_launch(void* const* d_in, const int* in_sizes, int n_in,
                              void* d_out, int out_size, void* d_ws, size_t ws_size,
                              hipStream_t stream) {
    const float* x  = (const float*)d_in[0];
    const int*   ei = (const int*)d_in[1];
    const float* W1 = (const float*)d_in[2];
    const float* b1 = (const float*)d_in[3];
    const float* W2 = (const float*)d_in[4];
    const float* b2 = (const float*)d_in[5];
    const float* Wp = (const float*)d_in[6];
    const float* bp = (const float*)d_in[7];
    const float* Wc = (const float*)d_in[8];
    const float* bc = (const float*)d_in[9];
    float* out = (float*)d_out;

    char* ws  = (char*)d_ws;
    int* cnt  = (int*)(ws + OFF_CNT);
    int* ovfc = (int*)(ws + OFF_OVFC);
    int* ovf  = (int*)(ws + OFF_OVF);
    int* col  = (int*)(ws + OFF_COL);
    u16* g    = (u16*)(ws + OFF_G);
    u16* h    = (u16*)(ws + OFF_H);

    const int GB = (N_NODES + 63) / 64;   // 1563

    hipMemsetAsync(ws, 0, OFF_OVF, stream);                       // cnt + ovfc
    k_fill<<<NE / 256, 256, 0, stream>>>(ei, cnt, col, ovfc, ovf);
    k_gemm<IN_CH, false><<<GB, 256, 0, stream>>>(x, W1, cnt, g);
    k_agg<<<N_NODES / 4, 256, 0, stream>>>(g, col, cnt, ovfc, ovf, b1, h);
    k_gemm<HID_D, true><<<GB, 256, 0, stream>>>(h, W2, cnt, g);
    k_agg<<<N_NODES / 4, 256, 0, stream>>>(g, col, cnt, ovfc, ovf, b2, h);
    k_mlp<<<GB, 256, 0, stream>>>(h, Wp, bp, Wc, bc, out);
}

// Round 9
// 245.756 us; speedup vs baseline: 4.6466x; 1.2061x over previous
//
#include <hip/hip_runtime.h>

#define N_NODES 100000
#define IN_CH   256
#define HID_D   64
#define NCLS    6
#define NE      1600000
#define WB      64          // padded bucket width per node
#define OVF_CAP 4096
#define NPART   8           // = #XCDs
#define PSZ     (N_NODES / NPART)   // 12500

typedef unsigned short u16;
typedef unsigned int   u32;
typedef __attribute__((ext_vector_type(8))) short bf16x8;
typedef __attribute__((ext_vector_type(4))) float f32x4;

// ws layout (bytes)
#define OFF_CNT   0u                       // 100000*4 = 400000
#define OFF_OVFC  400000u                  // 4
#define OFF_OVF   400128u                  // 4096*2*4 = 32768
#define OFF_COL   433152u                  // 100000*64*4 = 25,600,000
#define OFF_G     26033152u                // 100000*64*2 = 12,800,000 (bf16)
#define OFF_H     38833152u                // 12,800,000 (bf16) -> end 51,633,152
#define Z_OFF     600000u                  // d_out (f32): logits [0,600000), z rest

__device__ __forceinline__ u16 f2bf(float f) {
    u32 u = __float_as_uint(f);
    return (u16)((u + 0x7fffu + ((u >> 16) & 1u)) >> 16);   // RNE
}
__device__ __forceinline__ float bf2f(u16 h) {
    return __uint_as_float(((u32)h) << 16);
}

// ---- XCD-partitioned bucket fill ----
// Blocks with blockIdx&7==p handle only dst in [p*12500,(p+1)*12500). Under
// round-robin block->XCD dispatch, partition p's cnt/col slices stay resident
// in XCD p's L2: atomics are local, scattered 4B writes merge before
// write-back (was 96MB HBM writes for 6.4MB payload). Edge stream is read
// 8x but 7/8 served by shared L3. Correct under ANY block->XCD mapping.
__global__ __launch_bounds__(256) void k_fill(const int* __restrict__ ei,
                                              int* __restrict__ cnt,
                                              int* __restrict__ col,
                                              int* __restrict__ ovfc,
                                              int* __restrict__ ovf) {
    const int part = blockIdx.x & (NPART - 1);
    const int lo = part * PSZ;
    const int hi = lo + PSZ;
    const int e0 = (blockIdx.x >> 3) * 512 + threadIdx.x * 2;   // grid: (NE/512)*8
    int2 s2 = *(const int2*)(ei + e0);
    int2 d2 = *(const int2*)(ei + NE + e0);
#pragma unroll
    for (int j = 0; j < 2; ++j) {
        int s = j ? s2.y : s2.x;
        int d = j ? d2.y : d2.x;
        if (d < lo || d >= hi) continue;
        if ((u32)s >= (u32)N_NODES) continue;
        int p = atomicAdd(&cnt[d], 1);
        if (p < WB) {
            col[(size_t)d * WB + p] = s;
        } else {
            int k = atomicAdd(ovfc, 1);
            if (k < OVF_CAP) { ovf[2 * k] = s; ovf[2 * k + 1] = d; }
        }
    }
}

// ---- G(bf16) = dinv .* (A @ W); A f32 or bf16 [N,KDIM], W f32 [KDIM,64] ----
template <int KDIM, bool ABF16>
__global__ __launch_bounds__(256) void k_gemm(const void* __restrict__ A,
                                              const float* __restrict__ W,
                                              const int* __restrict__ cnt,
                                              u16* __restrict__ G) {
    constexpr int KK = KDIM / 32;
    __shared__ __align__(16) u16 sB[KK * 4 * 64 * 8];

    for (int idx = threadIdx.x; idx < KK * 2048; idx += 256) {
        int j = idx & 7, l = (idx >> 3) & 63, t = (idx >> 9) & 3, kk = idx >> 11;
        int k = kk * 32 + (l >> 4) * 8 + j;
        int c = t * 16 + (l & 15);
        sB[idx] = f2bf(W[k * 64 + c]);
    }
    __syncthreads();

    const int lane = threadIdx.x & 63;
    const int wv   = threadIdx.x >> 6;
    const int row0 = blockIdx.x * 64 + wv * 16;
    const int g4   = lane >> 4;
    const int r16  = lane & 15;

    int arow = row0 + r16;
    int arow_c = arow < N_NODES ? arow : 0;

    f32x4 acc[4] = {{0,0,0,0},{0,0,0,0},{0,0,0,0},{0,0,0,0}};

    for (int kk = 0; kk < KK; ++kk) {
        bf16x8 a;
        if (ABF16) {
            const u16* ap = (const u16*)A + (size_t)arow_c * KDIM + kk * 32 + g4 * 8;
            a = *(const bf16x8*)ap;
        } else {
            const float* ap = (const float*)A + (size_t)arow_c * KDIM + kk * 32 + g4 * 8;
            float4 f0 = *(const float4*)ap;
            float4 f1 = *(const float4*)(ap + 4);
            a[0] = (short)f2bf(f0.x); a[1] = (short)f2bf(f0.y);
            a[2] = (short)f2bf(f0.z); a[3] = (short)f2bf(f0.w);
            a[4] = (short)f2bf(f1.x); a[5] = (short)f2bf(f1.y);
            a[6] = (short)f2bf(f1.z); a[7] = (short)f2bf(f1.w);
        }
#pragma unroll
        for (int t = 0; t < 4; ++t) {
            bf16x8 b = *(const bf16x8*)&sB[((kk * 4 + t) * 64 + lane) * 8];
            acc[t] = __builtin_amdgcn_mfma_f32_16x16x32_bf16(a, b, acc[t], 0, 0, 0);
        }
    }

#pragma unroll
    for (int r = 0; r < 4; ++r) {
        int row = row0 + g4 * 4 + r;
        if (row < N_NODES) {
            float dinv = rsqrtf((float)(cnt[row] + 1));
#pragma unroll
            for (int t = 0; t < 4; ++t)
                G[(size_t)row * 64 + t * 16 + r16] = f2bf(acc[t][r] * dinv);
        }
    }
}

// ---- Hout(bf16) = relu(dinv[i]*(g[i] + sum_{e:dst=i} g[src_e]) + bias) ----
__global__ __launch_bounds__(256) void k_agg(const u16* __restrict__ G,
                                             const int* __restrict__ col,
                                             const int* __restrict__ cnt,
                                             const int* __restrict__ ovfc,
                                             const int* __restrict__ ovf,
                                             const float* __restrict__ bias,
                                             u16* __restrict__ Hout) {
    int node = blockIdx.x * 4 + (threadIdx.x >> 6);   // grid exact: N/4
    int lane = threadIdx.x & 63;

    int deg = cnt[node];
    int m = min(deg, WB);
    int mycol = col[(size_t)node * WB + lane];

    float acc = bf2f(G[(size_t)node * 64 + lane]);    // self loop

    int e = 0;
    for (; e + 4 <= m; e += 4) {
        int c0 = __shfl(mycol, e + 0), c1 = __shfl(mycol, e + 1);
        int c2 = __shfl(mycol, e + 2), c3 = __shfl(mycol, e + 3);
        float v0 = bf2f(G[(size_t)c0 * 64 + lane]);
        float v1 = bf2f(G[(size_t)c1 * 64 + lane]);
        float v2 = bf2f(G[(size_t)c2 * 64 + lane]);
        float v3 = bf2f(G[(size_t)c3 * 64 + lane]);
        acc += v0; acc += v1; acc += v2; acc += v3;
    }
    for (; e < m; ++e) {
        int c = __shfl(mycol, e);
        acc += bf2f(G[(size_t)c * 64 + lane]);
    }

    int no = *ovfc;
    if (no > 0) {                       // essentially never taken (deg>64)
        no = min(no, OVF_CAP);
        for (int j = 0; j < no; ++j)
            if (ovf[2 * j + 1] == node)
                acc += bf2f(G[(size_t)ovf[2 * j] * 64 + lane]);
    }

    float dinv = rsqrtf((float)(deg + 1));
    float v = fmaxf(acc * dinv + bias[lane], 0.f);
    Hout[(size_t)node * 64 + lane] = f2bf(v);
}

// ---- z = relu(H@Wp+bp) -> out f32 [Z_OFF..]; logits = z@Wc+bc -> out f32 ----
__global__ __launch_bounds__(256) void k_mlp(const u16* __restrict__ H,
                                             const float* __restrict__ Wp,
                                             const float* __restrict__ bp,
                                             const float* __restrict__ Wc,
                                             const float* __restrict__ bc,
                                             float* __restrict__ out) {
    __shared__ __align__(16) u16 sP[2 * 4 * 64 * 8];
    __shared__ __align__(16) u16 sC[2 * 64 * 8];
    __shared__ __align__(16) u16 zt[4][16][72];

    for (int idx = threadIdx.x; idx < 4096; idx += 256) {
        int j = idx & 7, l = (idx >> 3) & 63, t = (idx >> 9) & 3, kk = idx >> 11;
        int k = kk * 32 + (l >> 4) * 8 + j;
        int c = t * 16 + (l & 15);
        sP[idx] = f2bf(Wp[k * 64 + c]);
    }
    for (int idx = threadIdx.x; idx < 1024; idx += 256) {
        int j = idx & 7, l = (idx >> 3) & 63, kk = idx >> 9;
        int k = kk * 32 + (l >> 4) * 8 + j;
        int c = l & 15;
        sC[idx] = (c < NCLS) ? f2bf(Wc[k * NCLS + c]) : (u16)0;
    }
    __syncthreads();

    const int lane = threadIdx.x & 63;
    const int wv   = threadIdx.x >> 6;
    const int row0 = blockIdx.x * 64 + wv * 16;
    const int g4   = lane >> 4;
    const int r16  = lane & 15;

    int arow = row0 + r16;
    int arow_c = arow < N_NODES ? arow : (N_NODES - 1);

    f32x4 zac[4] = {{0,0,0,0},{0,0,0,0},{0,0,0,0},{0,0,0,0}};
#pragma unroll
    for (int kk = 0; kk < 2; ++kk) {
        bf16x8 a = *(const bf16x8*)((const u16*)H + (size_t)arow_c * 64 + kk * 32 + g4 * 8);
#pragma unroll
        for (int t = 0; t < 4; ++t) {
            bf16x8 b = *(const bf16x8*)&sP[((kk * 4 + t) * 64 + lane) * 8];
            zac[t] = __builtin_amdgcn_mfma_f32_16x16x32_bf16(a, b, zac[t], 0, 0, 0);
        }
    }

#pragma unroll
    for (int r = 0; r < 4; ++r) {
        int row = row0 + g4 * 4 + r;
#pragma unroll
        for (int t = 0; t < 4; ++t) {
            float v = zac[t][r] + bp[t * 16 + r16];
            v = fmaxf(v, 0.f);
            zt[wv][g4 * 4 + r][t * 16 + r16] = f2bf(v);
            if (row < N_NODES)
                out[(size_t)Z_OFF + (size_t)row * 64 + t * 16 + r16] = v;
        }
    }
    __syncthreads();

    f32x4 lac = {0, 0, 0, 0};
#pragma unroll
    for (int kk = 0; kk < 2; ++kk) {
        bf16x8 a = *(const bf16x8*)&zt[wv][r16][kk * 32 + g4 * 8];
        bf16x8 b = *(const bf16x8*)&sC[(kk * 64 + lane) * 8];
        lac = __builtin_amdgcn_mfma_f32_16x16x32_bf16(a, b, lac, 0, 0, 0);
    }
#pragma unroll
    for (int r = 0; r < 4; ++r) {
        int row = row0 + g4 * 4 + r;
        if (row < N_NODES && r16 < NCLS)
            out[(size_t)row * NCLS + r16] = lac[r] + bc[r16];
    }
}

extern "C" void kernel_launch(void* const* d_in, const int* in_sizes, int n_in,
                              void* d_out, int out_size, void* d_ws, size_t ws_size,
                              hipStream_t stream) {
    const float* x  = (const float*)d_in[0];
    const int*   ei = (const int*)d_in[1];
    const float* W1 = (const float*)d_in[2];
    const float* b1 = (const float*)d_in[3];
    const float* W2 = (const float*)d_in[4];
    const float* b2 = (const float*)d_in[5];
    const float* Wp = (const float*)d_in[6];
    const float* bp = (const float*)d_in[7];
    const float* Wc = (const float*)d_in[8];
    const float* bc = (const float*)d_in[9];
    float* out = (float*)d_out;

    char* ws  = (char*)d_ws;
    int* cnt  = (int*)(ws + OFF_CNT);
    int* ovfc = (int*)(ws + OFF_OVFC);
    int* ovf  = (int*)(ws + OFF_OVF);
    int* col  = (int*)(ws + OFF_COL);
    u16* g    = (u16*)(ws + OFF_G);
    u16* h    = (u16*)(ws + OFF_H);

    const int GB = (N_NODES + 63) / 64;   // 1563

    hipMemsetAsync(ws, 0, OFF_OVF, stream);                       // cnt + ovfc
    k_fill<<<(NE / 512) * NPART, 256, 0, stream>>>(ei, cnt, col, ovfc, ovf);
    k_gemm<IN_CH, false><<<GB, 256, 0, stream>>>(x, W1, cnt, g);
    k_agg<<<N_NODES / 4, 256, 0, stream>>>(g, col, cnt, ovfc, ovf, b1, h);
    k_gemm<HID_D, true><<<GB, 256, 0, stream>>>(h, W2, cnt, g);
    k_agg<<<N_NODES / 4, 256, 0, stream>>>(g, col, cnt, ovfc, ovf, b2, h);
    k_mlp<<<GB, 256, 0, stream>>>(h, Wp, bp, Wc, bc, out);
}